// Round 8
// baseline (131.115 us; speedup 1.0000x reference)
//
#include <hip/hip_runtime.h>
#include <hip/hip_cooperative_groups.h>

namespace cg = cooperative_groups;

typedef unsigned int uint32;

#define M_DIM 512
#define CHUNKS 16   // row-interleave factor for partial sums (block.y)
#define NW 4        // waves per block

// ---------------------------------------------------------------------------
// Scalar decode (f32-vs-bf16 safety net, kept from R3-R6 ABI debugging).
// ---------------------------------------------------------------------------
__device__ __forceinline__ float dec_scalar(uint32 w) {
    return ((w & 0xFFFFu) == 0u) ? __uint_as_float(w)
                                 : __uint_as_float((w & 0xFFFFu) << 16);
}

__device__ __forceinline__ bool sniff_f32(const uint32* words) {
    int votes = 0;
    for (int k = 0; k < 64; ++k) {
        uint32 e = (words[k] >> 7) & 0xFFu;
        if (!(e >= 118u && e <= 130u)) votes++;
    }
    return votes > 16;
}

__device__ __forceinline__ float bf2f(unsigned short h) {
    return __uint_as_float(((uint32)h) << 16);
}

// ---------------------------------------------------------------------------
// Phase-1 body: partial real toeplitz-adjoint sums over diagonals d = j - i.
//   padj[b,c,d] = sum_{i == c (mod 16), i+d < M} (Lre[b,i,i+d] + rho*Tre[..])
// f32 fast path: float4 loads from 4-aligned row start a0 = i - (c&3); lane
// register acc[k][e] maps statically to d = 4*lane + 256k + e - (c&3).
// ---------------------------------------------------------------------------
__device__ __forceinline__ void phase1_partial(
    const void* __restrict__ Lre, const void* __restrict__ Tre,
    float rho, bool f32m, int b, int c, int tid,
    float (*lds)[M_DIM], float* __restrict__ partial)
{
    const int w = tid >> 6, lane = tid & 63;
    for (int idx = tid; idx < NW * M_DIM; idx += 256) (&lds[0][0])[idx] = 0.0f;
    __syncthreads();

    const size_t base = (size_t)b * (M_DIM * M_DIM);

    if (f32m) {
        const int cm = c & 3;
        float acc[2][4];
        #pragma unroll
        for (int k = 0; k < 2; ++k)
            #pragma unroll
            for (int e = 0; e < 4; ++e) acc[k][e] = 0.0f;

        for (int t = 0; t < M_DIM / (CHUNKS * NW); ++t) {   // 8 rows per wave
            const int i = c + CHUNKS * (w + NW * t);
            const int a0 = i - cm;                          // 4-aligned start
            const int nq = (M_DIM - a0) >> 2;               // valid float4s
            const float4* rowL =
                (const float4*)((const float*)Lre + base + (size_t)i * M_DIM + a0);
            const float4* rowT =
                (const float4*)((const float*)Tre + base + (size_t)i * M_DIM + a0);
            #pragma unroll
            for (int k = 0; k < 2; ++k) {
                const int q = lane + (k << 6);
                if (q < nq) {
                    const float4 L = rowL[q];
                    const float4 T = rowT[q];
                    #pragma unroll
                    for (int e = 0; e < 4; ++e)
                        acc[k][e] += (&L.x)[e] + rho * (&T.x)[e];
                }
            }
        }
        #pragma unroll
        for (int k = 0; k < 2; ++k)
            #pragma unroll
            for (int e = 0; e < 4; ++e) {
                const int d = 4 * lane + (k << 8) + e - cm;
                if (d >= 0) lds[w][d] = acc[k][e];
            }
    } else {
        float acc[8];
        #pragma unroll
        for (int k = 0; k < 8; ++k) acc[k] = 0.0f;
        const unsigned short* lp = (const unsigned short*)Lre;
        const unsigned short* tp = (const unsigned short*)Tre;
        for (int t = 0; t < M_DIM / (CHUNKS * NW); ++t) {
            const int i = c + CHUNKS * (w + NW * t);
            const size_t roff = base + (size_t)i * M_DIM;
            const int dmax = (M_DIM - 1) - i;
            #pragma unroll
            for (int k = 0; k < 8; ++k) {
                const int d = lane + (k << 6);
                if (d <= dmax) {
                    const size_t idx = roff + (size_t)(i + d);
                    acc[k] += bf2f(lp[idx]) + rho * bf2f(tp[idx]);
                }
            }
        }
        #pragma unroll
        for (int k = 0; k < 8; ++k) lds[w][lane + (k << 6)] = acc[k];
    }
    __syncthreads();

    float* pout = partial + (size_t)(b * CHUNKS + c) * M_DIM;
    for (int d = tid; d < M_DIM; d += 256) {
        float s = 0.f;
        #pragma unroll
        for (int ww = 0; ww < NW; ++ww) s += lds[ww][d];
        pout[d] = s;
    }
}

// ---------------------------------------------------------------------------
// Phase-2 body: redundant per-block reduce of batch b's 16 partials (L2-hot)
// -> u_re in LDS -> write 32 rows: out[b,i,j] = u_re[|j-i|].
// ---------------------------------------------------------------------------
__device__ __forceinline__ void phase2_expand(
    const float* __restrict__ partial, float rho, float tau,
    int b, int c, int tid, float* __restrict__ ure,
    float* __restrict__ out, unsigned int out_elems)
{
    const float* p = partial + (size_t)b * CHUNKS * M_DIM;
    for (int d = tid; d < M_DIM; d += 256) {
        float s = 0.f;
        #pragma unroll
        for (int cc = 0; cc < CHUNKS; ++cc) s += p[(size_t)cc * M_DIM + d];
        if (d == 0) s -= 0.5f * tau * (float)M_DIM;
        ure[d] = s / ((float)(M_DIM - d) * rho);
    }
    __syncthreads();

    const int w = tid >> 6, lane = tid & 63;
    for (int t = 0; t < 8; ++t) {                        // 8 rows per wave
        const int i = c * 32 + w * 8 + t;
        const size_t rbase = (size_t)(b * M_DIM + i) * M_DIM;
        if (rbase + M_DIM > (size_t)out_elems) continue; // safety clamp
        float4* rowp = (float4*)(out + rbase);
        #pragma unroll
        for (int k = 0; k < 2; ++k) {
            const int q = lane + (k << 6);
            const int j0 = q << 2;
            float4 v;
            #pragma unroll
            for (int e = 0; e < 4; ++e) {
                const int dd = j0 + e - i;
                (&v.x)[e] = ure[dd < 0 ? -dd : dd];
            }
            rowp[q] = v;
        }
    }
}

// ---------------------------------------------------------------------------
// Fused cooperative kernel: phase 1 -> grid.sync() -> phase 2.
// Removes the inter-kernel drain gap + second launch of the 2-kernel path.
// ---------------------------------------------------------------------------
__global__ __launch_bounds__(256) void k_coop(
    const void* __restrict__ Lre, const void* __restrict__ Tre,
    const uint32* __restrict__ rho_p, const uint32* __restrict__ tau_p,
    float* __restrict__ partial, float* __restrict__ out,
    unsigned int out_elems)
{
    __shared__ float lds[NW][M_DIM];   // 8 KB; row 0 reused as ure in phase 2
    const int b = blockIdx.x, c = blockIdx.y, tid = threadIdx.x;
    const float rho = dec_scalar(rho_p[0]);
    const float tau = dec_scalar(tau_p[0]);
    const bool f32m = sniff_f32((const uint32*)Lre);

    phase1_partial(Lre, Tre, rho, f32m, b, c, tid, lds, partial);

    cg::this_grid().sync();   // device-scope coherent barrier (G16-sanctioned)

    phase2_expand(partial, rho, tau, b, c, tid, &lds[0][0], out, out_elems);
}

// ---------------------------------------------------------------------------
// Fallback kernels (proven R7 path).
// ---------------------------------------------------------------------------
__global__ __launch_bounds__(256) void kA_partial(
    const void* __restrict__ Lre, const void* __restrict__ Tre,
    const uint32* __restrict__ rho_p, float* __restrict__ partial)
{
    __shared__ float lds[NW][M_DIM];
    const int b = blockIdx.x, c = blockIdx.y, tid = threadIdx.x;
    const float rho = dec_scalar(rho_p[0]);
    const bool f32m = sniff_f32((const uint32*)Lre);
    phase1_partial(Lre, Tre, rho, f32m, b, c, tid, lds, partial);
}

__global__ __launch_bounds__(256) void kB_expand(
    const float* __restrict__ partial,
    const uint32* __restrict__ rho_p, const uint32* __restrict__ tau_p,
    float* __restrict__ out, unsigned int out_elems)
{
    __shared__ float ure[M_DIM];
    const int b = blockIdx.x, c = blockIdx.y, tid = threadIdx.x;
    const float rho = dec_scalar(rho_p[0]);
    const float tau = dec_scalar(tau_p[0]);
    phase2_expand(partial, rho, tau, b, c, tid, ure, out, out_elems);
}

// Zero-workspace fallback: one block per batch, fully fused.
__global__ __launch_bounds__(256) void k_fused(
    const uint32* __restrict__ rho_p, const uint32* __restrict__ tau_p,
    const void* __restrict__ Lre, const void* __restrict__ Tre,
    float* __restrict__ out, unsigned int out_elems)
{
    __shared__ float lds[NW][M_DIM];
    __shared__ float ure[M_DIM];
    const int b = blockIdx.x, tid = threadIdx.x, w = tid >> 6, lane = tid & 63;
    const float rho = dec_scalar(rho_p[0]);
    const float tau = dec_scalar(tau_p[0]);
    const bool f32m = sniff_f32((const uint32*)Lre);

    float acc[8];
    #pragma unroll
    for (int k = 0; k < 8; ++k) acc[k] = 0.0f;
    const size_t base = (size_t)b * (M_DIM * M_DIM);
    for (int t = 0; t < M_DIM / NW; ++t) {
        const int i = w + NW * t;
        const size_t roff = base + (size_t)i * M_DIM;
        const int dmax = (M_DIM - 1) - i;
        #pragma unroll
        for (int k = 0; k < 8; ++k) {
            const int d = lane + (k << 6);
            if (d <= dmax) {
                const size_t idx = roff + (size_t)(i + d);
                const float lv = f32m ? ((const float*)Lre)[idx]
                                      : bf2f(((const unsigned short*)Lre)[idx]);
                const float tv = f32m ? ((const float*)Tre)[idx]
                                      : bf2f(((const unsigned short*)Tre)[idx]);
                acc[k] += lv + rho * tv;
            }
        }
    }
    #pragma unroll
    for (int k = 0; k < 8; ++k) lds[w][lane + (k << 6)] = acc[k];
    __syncthreads();

    for (int d = tid; d < M_DIM; d += 256) {
        float s = 0.f;
        #pragma unroll
        for (int ww = 0; ww < NW; ++ww) s += lds[ww][d];
        if (d == 0) s -= 0.5f * tau * (float)M_DIM;
        ure[d] = s / ((float)(M_DIM - d) * rho);
    }
    __syncthreads();

    for (int t = 0; t < M_DIM / NW; ++t) {
        const int i = w + NW * t;
        const size_t rbase = (size_t)(b * M_DIM + i) * M_DIM;
        if (rbase + M_DIM > (size_t)out_elems) continue;
        float4* rowp = (float4*)(out + rbase);
        #pragma unroll
        for (int k = 0; k < 2; ++k) {
            const int q = lane + (k << 6);
            const int j0 = q << 2;
            float4 v;
            #pragma unroll
            for (int e = 0; e < 4; ++e) {
                const int dd = j0 + e - i;
                (&v.x)[e] = ure[dd < 0 ? -dd : dd];
            }
            rowp[q] = v;
        }
    }
}

extern "C" void kernel_launch(void* const* d_in, const int* in_sizes, int n_in,
                              void* d_out, int out_size, void* d_ws, size_t ws_size,
                              hipStream_t stream)
{
    const uint32* rho = (const uint32*)d_in[0];
    const uint32* tau = (const uint32*)d_in[1];
    const void* Lre = d_in[2];
    // d_in[3] (Lamda_im), d_in[5] (Theta_im): never needed — output is re(T).
    const void* Tre = d_in[4];
    const int B = in_sizes[2] / (M_DIM * M_DIM);   // 64
    float* out = (float*)d_out;
    unsigned int out_elems = (unsigned int)out_size;  // f32 elements

    const size_t partial_bytes = (size_t)B * CHUNKS * M_DIM * sizeof(float); // 2 MB

    dim3 grid(B, CHUNKS);
    if (ws_size >= partial_bytes) {
        float* partial = (float*)d_ws;
        void* args[] = { (void*)&Lre, (void*)&Tre, (void*)&rho, (void*)&tau,
                         (void*)&partial, (void*)&out, (void*)&out_elems };
        hipError_t err = hipLaunchCooperativeKernel(
            (const void*)k_coop, grid, dim3(256), args, 0, stream);
        if (err != hipSuccess) {
            // nothing was enqueued; fall back to the proven 2-kernel path
            kA_partial<<<grid, 256, 0, stream>>>(Lre, Tre, rho, partial);
            kB_expand<<<grid, 256, 0, stream>>>(partial, rho, tau, out, out_elems);
        }
    } else {
        k_fused<<<B, 256, 0, stream>>>(rho, tau, Lre, Tre, out, out_elems);
    }
}

// Round 9
// 33.853 us; speedup vs baseline: 3.8731x; 3.8731x over previous
//
#include <hip/hip_runtime.h>

typedef unsigned int uint32;

#define M_DIM 512
#define CHUNKS 16   // row-interleave factor for partial sums (block.y)
#define NW 4        // waves per block
#define VSTRIDE 1032  // ves row stride in floats (4128 B, 16B-aligned)

// ---------------------------------------------------------------------------
// Scalar decode (f32-vs-bf16 safety net, kept from R3-R6 ABI debugging).
// ---------------------------------------------------------------------------
__device__ __forceinline__ float dec_scalar(uint32 w) {
    return ((w & 0xFFFFu) == 0u) ? __uint_as_float(w)
                                 : __uint_as_float((w & 0xFFFFu) << 16);
}

__device__ __forceinline__ bool sniff_f32(const uint32* words) {
    int votes = 0;
    for (int k = 0; k < 64; ++k) {
        uint32 e = (words[k] >> 7) & 0xFFu;
        if (!(e >= 118u && e <= 130u)) votes++;
    }
    return votes > 16;
}

__device__ __forceinline__ float bf2f(unsigned short h) {
    return __uint_as_float(((uint32)h) << 16);
}

// ---------------------------------------------------------------------------
// Phase-1 body: partial real toeplitz-adjoint sums over diagonals d = j - i.
//   padj[b,c,d] = sum_{i == c (mod 16), i+d < M} (Lre[b,i,i+d] + rho*Tre[..])
// f32 fast path: float4 loads from 4-aligned row start a0 = i - (c&3); lane
// register acc[k][e] maps statically to d = 4*lane + 256k + e - (c&3).
// ---------------------------------------------------------------------------
__device__ __forceinline__ void phase1_partial(
    const void* __restrict__ Lre, const void* __restrict__ Tre,
    float rho, bool f32m, int b, int c, int tid,
    float (*lds)[M_DIM], float* __restrict__ partial)
{
    const int w = tid >> 6, lane = tid & 63;
    for (int idx = tid; idx < NW * M_DIM; idx += 256) (&lds[0][0])[idx] = 0.0f;
    __syncthreads();

    const size_t base = (size_t)b * (M_DIM * M_DIM);

    if (f32m) {
        const int cm = c & 3;
        float acc[2][4];
        #pragma unroll
        for (int k = 0; k < 2; ++k)
            #pragma unroll
            for (int e = 0; e < 4; ++e) acc[k][e] = 0.0f;

        for (int t = 0; t < M_DIM / (CHUNKS * NW); ++t) {   // 8 rows per wave
            const int i = c + CHUNKS * (w + NW * t);
            const int a0 = i - cm;                          // 4-aligned start
            const int nq = (M_DIM - a0) >> 2;               // valid float4s
            const float4* rowL =
                (const float4*)((const float*)Lre + base + (size_t)i * M_DIM + a0);
            const float4* rowT =
                (const float4*)((const float*)Tre + base + (size_t)i * M_DIM + a0);
            #pragma unroll
            for (int k = 0; k < 2; ++k) {
                const int q = lane + (k << 6);
                if (q < nq) {
                    const float4 L = rowL[q];
                    const float4 T = rowT[q];
                    #pragma unroll
                    for (int e = 0; e < 4; ++e)
                        acc[k][e] += (&L.x)[e] + rho * (&T.x)[e];
                }
            }
        }
        #pragma unroll
        for (int k = 0; k < 2; ++k)
            #pragma unroll
            for (int e = 0; e < 4; ++e) {
                const int d = 4 * lane + (k << 8) + e - cm;
                if (d >= 0) lds[w][d] = acc[k][e];
            }
    } else {
        float acc[8];
        #pragma unroll
        for (int k = 0; k < 8; ++k) acc[k] = 0.0f;
        const unsigned short* lp = (const unsigned short*)Lre;
        const unsigned short* tp = (const unsigned short*)Tre;
        for (int t = 0; t < M_DIM / (CHUNKS * NW); ++t) {
            const int i = c + CHUNKS * (w + NW * t);
            const size_t roff = base + (size_t)i * M_DIM;
            const int dmax = (M_DIM - 1) - i;
            #pragma unroll
            for (int k = 0; k < 8; ++k) {
                const int d = lane + (k << 6);
                if (d <= dmax) {
                    const size_t idx = roff + (size_t)(i + d);
                    acc[k] += bf2f(lp[idx]) + rho * bf2f(tp[idx]);
                }
            }
        }
        #pragma unroll
        for (int k = 0; k < 8; ++k) lds[w][lane + (k << 6)] = acc[k];
    }
    __syncthreads();

    float* pout = partial + (size_t)(b * CHUNKS + c) * M_DIM;
    for (int d = tid; d < M_DIM; d += 256) {
        float s = 0.f;
        #pragma unroll
        for (int ww = 0; ww < NW; ++ww) s += lds[ww][d];
        pout[d] = s;
    }
}

// ---------------------------------------------------------------------------
// ves build: 4 shifted copies of the extended diagonal array
//   ve[k] = u[|k - 511|], k in [0,1022];  ves[s][k] = ve[k + s]
// Row i (o = 511-i) then reads out[i][j] = ve[o+j] as ALIGNED float4s from
// copy s = o&3: float4-index ((o-s)>>2) + q  -> conflict-free ds_read_b128
// (replaces the stride-4 scalar reads that were 8-way bank-conflicted).
// ---------------------------------------------------------------------------
__device__ __forceinline__ void build_ves(
    const float* __restrict__ ure, float (*ves)[VSTRIDE], int tid)
{
    for (int k = tid; k < 1024; k += 256) {
        #pragma unroll
        for (int s = 0; s < 4; ++s) {
            int a = k + s - 511;
            a = a < 0 ? -a : a;
            ves[s][k] = (a < M_DIM) ? ure[a] : 0.0f;
        }
    }
}

__device__ __forceinline__ void write_rows(
    const float (*ves)[VSTRIDE], int b, int c, int tid,
    float* __restrict__ out, unsigned int out_elems)
{
    const int w = tid >> 6, lane = tid & 63;
    for (int t = 0; t < 8; ++t) {                        // 8 rows per wave
        const int i = c * 32 + w * 8 + t;
        const size_t rbase = (size_t)(b * M_DIM + i) * M_DIM;
        if (rbase + M_DIM > (size_t)out_elems) continue; // safety clamp
        float4* rowp = (float4*)(out + rbase);
        const int o = (M_DIM - 1) - i;
        const int s = o & 3;
        const float4* vp = (const float4*)(&ves[s][0]);
        const int b4 = (o - s) >> 2;
        rowp[lane]      = vp[b4 + lane];
        rowp[lane + 64] = vp[b4 + lane + 64];
    }
}

// ---------------------------------------------------------------------------
// kA: phase-1 partials -> ws.
// ---------------------------------------------------------------------------
__global__ __launch_bounds__(256) void kA_partial(
    const void* __restrict__ Lre, const void* __restrict__ Tre,
    const uint32* __restrict__ rho_p, float* __restrict__ partial)
{
    __shared__ float lds[NW][M_DIM];
    const int b = blockIdx.x, c = blockIdx.y, tid = threadIdx.x;
    const float rho = dec_scalar(rho_p[0]);
    const bool f32m = sniff_f32((const uint32*)Lre);
    phase1_partial(Lre, Tre, rho, f32m, b, c, tid, lds, partial);
}

// ---------------------------------------------------------------------------
// kB: redundant per-block reduce of batch b's 16 partials (L2-hot) -> u_re
// -> ves copies -> 32 rows of out[b,i,j] = u_re[|j-i|], all-b128 LDS reads.
// ---------------------------------------------------------------------------
__global__ __launch_bounds__(256) void kB_expand(
    const float* __restrict__ partial,
    const uint32* __restrict__ rho_p, const uint32* __restrict__ tau_p,
    float* __restrict__ out, unsigned int out_elems)
{
    __shared__ float ure[M_DIM];
    __shared__ __align__(16) float ves[4][VSTRIDE];   // 16.5 KB
    const int b = blockIdx.x, c = blockIdx.y, tid = threadIdx.x;
    const float rho = dec_scalar(rho_p[0]);
    const float tau = dec_scalar(tau_p[0]);

    const float* p = partial + (size_t)b * CHUNKS * M_DIM;
    for (int d = tid; d < M_DIM; d += 256) {
        float s = 0.f;
        #pragma unroll
        for (int cc = 0; cc < CHUNKS; ++cc) s += p[(size_t)cc * M_DIM + d];
        if (d == 0) s -= 0.5f * tau * (float)M_DIM;
        ure[d] = s / ((float)(M_DIM - d) * rho);
    }
    __syncthreads();
    build_ves(ure, ves, tid);
    __syncthreads();
    write_rows(ves, b, c, tid, out, out_elems);
}

// ---------------------------------------------------------------------------
// Mid fallback (ws in [128 KB, 2 MB)): partials transient in d_out.
// ---------------------------------------------------------------------------
__global__ __launch_bounds__(256) void k2_reduce(
    const float* __restrict__ partial,
    const uint32* __restrict__ rho_p, const uint32* __restrict__ tau_p,
    float* __restrict__ u)
{
    const int b = blockIdx.x, tid = threadIdx.x;
    const float rho = dec_scalar(rho_p[0]);
    const float tau = dec_scalar(tau_p[0]);
    const float* p = partial + (size_t)b * CHUNKS * M_DIM;
    for (int d = tid; d < M_DIM; d += 256) {
        float s = 0.f;
        #pragma unroll
        for (int cc = 0; cc < CHUNKS; ++cc) s += p[(size_t)cc * M_DIM + d];
        if (d == 0) s -= 0.5f * tau * (float)M_DIM;
        u[(size_t)b * M_DIM + d] = s / ((float)(M_DIM - d) * rho);
    }
}

__global__ __launch_bounds__(256) void k3_write(
    const float* __restrict__ u, float* __restrict__ out,
    unsigned int out_elems)
{
    __shared__ float ure[M_DIM];
    __shared__ __align__(16) float ves[4][VSTRIDE];
    const int b = blockIdx.x, c = blockIdx.y, tid = threadIdx.x;
    for (int d = tid; d < M_DIM; d += 256) ure[d] = u[(size_t)b * M_DIM + d];
    __syncthreads();
    build_ves(ure, ves, tid);
    __syncthreads();
    write_rows(ves, b, c, tid, out, out_elems);
}

// ---------------------------------------------------------------------------
// Zero-workspace fallback: one block per batch, fully fused.
// ---------------------------------------------------------------------------
__global__ __launch_bounds__(256) void k_fused(
    const uint32* __restrict__ rho_p, const uint32* __restrict__ tau_p,
    const void* __restrict__ Lre, const void* __restrict__ Tre,
    float* __restrict__ out, unsigned int out_elems)
{
    __shared__ float lds[NW][M_DIM];
    __shared__ float ure[M_DIM];
    const int b = blockIdx.x, tid = threadIdx.x, w = tid >> 6, lane = tid & 63;
    const float rho = dec_scalar(rho_p[0]);
    const float tau = dec_scalar(tau_p[0]);
    const bool f32m = sniff_f32((const uint32*)Lre);

    float acc[8];
    #pragma unroll
    for (int k = 0; k < 8; ++k) acc[k] = 0.0f;
    const size_t base = (size_t)b * (M_DIM * M_DIM);
    for (int t = 0; t < M_DIM / NW; ++t) {
        const int i = w + NW * t;
        const size_t roff = base + (size_t)i * M_DIM;
        const int dmax = (M_DIM - 1) - i;
        #pragma unroll
        for (int k = 0; k < 8; ++k) {
            const int d = lane + (k << 6);
            if (d <= dmax) {
                const size_t idx = roff + (size_t)(i + d);
                const float lv = f32m ? ((const float*)Lre)[idx]
                                      : bf2f(((const unsigned short*)Lre)[idx]);
                const float tv = f32m ? ((const float*)Tre)[idx]
                                      : bf2f(((const unsigned short*)Tre)[idx]);
                acc[k] += lv + rho * tv;
            }
        }
    }
    #pragma unroll
    for (int k = 0; k < 8; ++k) lds[w][lane + (k << 6)] = acc[k];
    __syncthreads();

    for (int d = tid; d < M_DIM; d += 256) {
        float s = 0.f;
        #pragma unroll
        for (int ww = 0; ww < NW; ++ww) s += lds[ww][d];
        if (d == 0) s -= 0.5f * tau * (float)M_DIM;
        ure[d] = s / ((float)(M_DIM - d) * rho);
    }
    __syncthreads();

    for (int t = 0; t < M_DIM / NW; ++t) {
        const int i = w + NW * t;
        const size_t rbase = (size_t)(b * M_DIM + i) * M_DIM;
        if (rbase + M_DIM > (size_t)out_elems) continue;
        float4* rowp = (float4*)(out + rbase);
        #pragma unroll
        for (int k = 0; k < 2; ++k) {
            const int q = lane + (k << 6);
            const int j0 = q << 2;
            float4 v;
            #pragma unroll
            for (int e = 0; e < 4; ++e) {
                const int dd = j0 + e - i;
                (&v.x)[e] = ure[dd < 0 ? -dd : dd];
            }
            rowp[q] = v;
        }
    }
}

extern "C" void kernel_launch(void* const* d_in, const int* in_sizes, int n_in,
                              void* d_out, int out_size, void* d_ws, size_t ws_size,
                              hipStream_t stream)
{
    const uint32* rho = (const uint32*)d_in[0];
    const uint32* tau = (const uint32*)d_in[1];
    const void* Lre = d_in[2];
    // d_in[3] (Lamda_im), d_in[5] (Theta_im): never needed — output is re(T).
    const void* Tre = d_in[4];
    const int B = in_sizes[2] / (M_DIM * M_DIM);   // 64
    float* out = (float*)d_out;
    const unsigned int out_elems = (unsigned int)out_size;  // f32 elements

    const size_t partial_bytes = (size_t)B * CHUNKS * M_DIM * sizeof(float); // 2 MB
    const size_t u_bytes = (size_t)B * M_DIM * sizeof(float);                // 128 KB

    dim3 grid(B, CHUNKS);
    if (ws_size >= partial_bytes) {
        // Fast path: 2 kernels, partials in ws. (R8 lesson: a dependent-kernel
        // boundary is cheaper than any device-scope in-kernel barrier here.)
        float* partial = (float*)d_ws;
        kA_partial<<<grid, 256, 0, stream>>>(Lre, Tre, rho, partial);
        kB_expand<<<grid, 256, 0, stream>>>(partial, rho, tau, out, out_elems);
    } else if (ws_size >= u_bytes &&
               (size_t)out_size * sizeof(float) >= partial_bytes) {
        float* partial = out;
        float* u = (float*)d_ws;
        kA_partial<<<grid, 256, 0, stream>>>(Lre, Tre, rho, partial);
        k2_reduce<<<B, 256, 0, stream>>>(partial, rho, tau, u);
        k3_write<<<grid, 256, 0, stream>>>(u, out, out_elems);
    } else {
        k_fused<<<B, 256, 0, stream>>>(rho, tau, Lre, Tre, out, out_elems);
    }
}

// Round 11
// 32.486 us; speedup vs baseline: 4.0361x; 1.0421x over previous
//
#include <hip/hip_runtime.h>

typedef unsigned int uint32;
typedef float f32x4 __attribute__((ext_vector_type(4)));  // clang-native for nontemporal

#define M_DIM 512
#define CHUNKS 16   // row-interleave factor for partial sums (block.y)
#define NW 4        // waves per block

// ---------------------------------------------------------------------------
// Scalar decode (kept from ABI debugging; free): f32 1.0f has low16 == 0,
// a bf16 scalar would sit in the low 16 bits (nonzero).
// ---------------------------------------------------------------------------
__device__ __forceinline__ float dec_scalar(uint32 w) {
    return ((w & 0xFFFFu) == 0u) ? __uint_as_float(w)
                                 : __uint_as_float((w & 0xFFFFu) << 16);
}

// ---------------------------------------------------------------------------
// kA: partial real toeplitz-adjoint sums over diagonals d = j - i.
//   padj[b,c,d] = sum_{i == c (mod 16), i+d < M} (Lre[b,i,i+d] + rho*Tre[..])
// float4 loads from the 4-aligned row start a0 = i - (c&3); lane register
// acc[k][e] maps statically to d = 4*lane + 256k + e - (c&3):
//   - d < 0 elements are lower-triangle garbage, accumulated but not written;
//   - top (c&3) diagonals have no contributing rows here -> stay zero-inited.
// (Inputs are f32 — established R6.)
// ---------------------------------------------------------------------------
__global__ __launch_bounds__(256) void kA_partial(
    const float* __restrict__ Lre, const float* __restrict__ Tre,
    const uint32* __restrict__ rho_p, float* __restrict__ partial)
{
    __shared__ float lds[NW][M_DIM];   // 8 KB
    const int b = blockIdx.x, c = blockIdx.y;
    const int tid = threadIdx.x, w = tid >> 6, lane = tid & 63;
    const float rho = dec_scalar(rho_p[0]);

    for (int idx = tid; idx < NW * M_DIM; idx += 256) (&lds[0][0])[idx] = 0.0f;
    __syncthreads();

    const size_t base = (size_t)b * (M_DIM * M_DIM);
    const int cm = c & 3;

    float acc[2][4];
    #pragma unroll
    for (int k = 0; k < 2; ++k)
        #pragma unroll
        for (int e = 0; e < 4; ++e) acc[k][e] = 0.0f;

    for (int t = 0; t < M_DIM / (CHUNKS * NW); ++t) {   // 8 rows per wave
        const int i = c + CHUNKS * (w + NW * t);
        const int a0 = i - cm;                          // 4-aligned start
        const int nq = (M_DIM - a0) >> 2;               // valid float4s
        const float4* rowL = (const float4*)(Lre + base + (size_t)i * M_DIM + a0);
        const float4* rowT = (const float4*)(Tre + base + (size_t)i * M_DIM + a0);
        #pragma unroll
        for (int k = 0; k < 2; ++k) {
            const int q = lane + (k << 6);
            if (q < nq) {
                const float4 L = rowL[q];
                const float4 T = rowT[q];
                #pragma unroll
                for (int e = 0; e < 4; ++e)
                    acc[k][e] += (&L.x)[e] + rho * (&T.x)[e];
            }
        }
    }
    #pragma unroll
    for (int k = 0; k < 2; ++k)
        #pragma unroll
        for (int e = 0; e < 4; ++e) {
            const int d = 4 * lane + (k << 8) + e - cm;
            if (d >= 0) lds[w][d] = acc[k][e];
        }
    __syncthreads();

    float* pout = partial + (size_t)(b * CHUNKS + c) * M_DIM;
    for (int d = tid; d < M_DIM; d += 256) {
        float s = 0.f;
        #pragma unroll
        for (int ww = 0; ww < NW; ++ww) s += lds[ww][d];
        pout[d] = s;
    }
}

// ---------------------------------------------------------------------------
// kB: redundant per-block reduce of batch b's 16 partials (L2-hot, ~1 µs
// aggregate) -> u_re in LDS -> write 32 rows: out[b,i,j] = u_re[|j-i|].
// LDS reads are 8-way bank-conflicted but MASKED by store latency (proven
// R9: conflict-free ves variant was neutral). Non-temporal stores: output
// is write-once, never re-read -> don't displace L3-resident inputs.
// ---------------------------------------------------------------------------
__global__ __launch_bounds__(256) void kB_expand(
    const float* __restrict__ partial,
    const uint32* __restrict__ rho_p, const uint32* __restrict__ tau_p,
    float* __restrict__ out, unsigned int out_elems)
{
    __shared__ float ure[M_DIM];
    const int b = blockIdx.x, c = blockIdx.y;
    const int tid = threadIdx.x;
    const float rho = dec_scalar(rho_p[0]);
    const float tau = dec_scalar(tau_p[0]);

    const float* p = partial + (size_t)b * CHUNKS * M_DIM;
    for (int d = tid; d < M_DIM; d += 256) {
        float s = 0.f;
        #pragma unroll
        for (int cc = 0; cc < CHUNKS; ++cc) s += p[(size_t)cc * M_DIM + d];
        if (d == 0) s -= 0.5f * tau * (float)M_DIM;
        ure[d] = s / ((float)(M_DIM - d) * rho);
    }
    __syncthreads();

    const int w = tid >> 6, lane = tid & 63;
    for (int t = 0; t < 8; ++t) {                        // 8 rows per wave
        const int i = c * 32 + w * 8 + t;
        const size_t rbase = (size_t)(b * M_DIM + i) * M_DIM;
        if (rbase + M_DIM > (size_t)out_elems) continue; // safety clamp
        f32x4* rowp = (f32x4*)(out + rbase);
        #pragma unroll
        for (int k = 0; k < 2; ++k) {
            const int q = lane + (k << 6);
            const int j0 = q << 2;
            f32x4 v;
            #pragma unroll
            for (int e = 0; e < 4; ++e) {
                const int dd = j0 + e - i;
                v[e] = ure[dd < 0 ? -dd : dd];
            }
            __builtin_nontemporal_store(v, rowp + q);
        }
    }
}

// ---------------------------------------------------------------------------
// Mid fallback (ws in [128 KB, 2 MB)): partials transient in d_out.
// ---------------------------------------------------------------------------
__global__ __launch_bounds__(256) void k2_reduce(
    const float* __restrict__ partial,
    const uint32* __restrict__ rho_p, const uint32* __restrict__ tau_p,
    float* __restrict__ u)
{
    const int b = blockIdx.x, tid = threadIdx.x;
    const float rho = dec_scalar(rho_p[0]);
    const float tau = dec_scalar(tau_p[0]);
    const float* p = partial + (size_t)b * CHUNKS * M_DIM;
    for (int d = tid; d < M_DIM; d += 256) {
        float s = 0.f;
        #pragma unroll
        for (int cc = 0; cc < CHUNKS; ++cc) s += p[(size_t)cc * M_DIM + d];
        if (d == 0) s -= 0.5f * tau * (float)M_DIM;
        u[(size_t)b * M_DIM + d] = s / ((float)(M_DIM - d) * rho);
    }
}

__global__ __launch_bounds__(256) void k3_write(
    const float* __restrict__ u, float* __restrict__ out,
    unsigned int out_elems)
{
    __shared__ float ure[M_DIM];
    const int b = blockIdx.x, c = blockIdx.y, tid = threadIdx.x;
    for (int d = tid; d < M_DIM; d += 256) ure[d] = u[(size_t)b * M_DIM + d];
    __syncthreads();
    const int w = tid >> 6, lane = tid & 63;
    for (int t = 0; t < 8; ++t) {
        const int i = c * 32 + w * 8 + t;
        const size_t rbase = (size_t)(b * M_DIM + i) * M_DIM;
        if (rbase + M_DIM > (size_t)out_elems) continue;
        float4* rowp = (float4*)(out + rbase);
        #pragma unroll
        for (int k = 0; k < 2; ++k) {
            const int q = lane + (k << 6);
            const int j0 = q << 2;
            float4 v;
            #pragma unroll
            for (int e = 0; e < 4; ++e) {
                const int dd = j0 + e - i;
                (&v.x)[e] = ure[dd < 0 ? -dd : dd];
            }
            rowp[q] = v;
        }
    }
}

// ---------------------------------------------------------------------------
// Zero-workspace fallback: one block per batch, fully fused.
// ---------------------------------------------------------------------------
__global__ __launch_bounds__(256) void k_fused(
    const uint32* __restrict__ rho_p, const uint32* __restrict__ tau_p,
    const float* __restrict__ Lre, const float* __restrict__ Tre,
    float* __restrict__ out, unsigned int out_elems)
{
    __shared__ float lds[NW][M_DIM];
    __shared__ float ure[M_DIM];
    const int b = blockIdx.x, tid = threadIdx.x, w = tid >> 6, lane = tid & 63;
    const float rho = dec_scalar(rho_p[0]);
    const float tau = dec_scalar(tau_p[0]);

    float acc[8];
    #pragma unroll
    for (int k = 0; k < 8; ++k) acc[k] = 0.0f;
    const size_t base = (size_t)b * (M_DIM * M_DIM);
    for (int t = 0; t < M_DIM / NW; ++t) {
        const int i = w + NW * t;
        const size_t roff = base + (size_t)i * M_DIM;
        const int dmax = (M_DIM - 1) - i;
        #pragma unroll
        for (int k = 0; k < 8; ++k) {
            const int d = lane + (k << 6);
            if (d <= dmax) {
                const size_t idx = roff + (size_t)(i + d);
                acc[k] += Lre[idx] + rho * Tre[idx];
            }
        }
    }
    #pragma unroll
    for (int k = 0; k < 8; ++k) lds[w][lane + (k << 6)] = acc[k];
    __syncthreads();

    for (int d = tid; d < M_DIM; d += 256) {
        float s = 0.f;
        #pragma unroll
        for (int ww = 0; ww < NW; ++ww) s += lds[ww][d];
        if (d == 0) s -= 0.5f * tau * (float)M_DIM;
        ure[d] = s / ((float)(M_DIM - d) * rho);
    }
    __syncthreads();

    for (int t = 0; t < M_DIM / NW; ++t) {
        const int i = w + NW * t;
        const size_t rbase = (size_t)(b * M_DIM + i) * M_DIM;
        if (rbase + M_DIM > (size_t)out_elems) continue;
        float4* rowp = (float4*)(out + rbase);
        #pragma unroll
        for (int k = 0; k < 2; ++k) {
            const int q = lane + (k << 6);
            const int j0 = q << 2;
            float4 v;
            #pragma unroll
            for (int e = 0; e < 4; ++e) {
                const int dd = j0 + e - i;
                (&v.x)[e] = ure[dd < 0 ? -dd : dd];
            }
            rowp[q] = v;
        }
    }
}

extern "C" void kernel_launch(void* const* d_in, const int* in_sizes, int n_in,
                              void* d_out, int out_size, void* d_ws, size_t ws_size,
                              hipStream_t stream)
{
    const uint32* rho = (const uint32*)d_in[0];
    const uint32* tau = (const uint32*)d_in[1];
    const float* Lre = (const float*)d_in[2];
    // d_in[3] (Lamda_im), d_in[5] (Theta_im): never needed — output is re(T).
    const float* Tre = (const float*)d_in[4];
    const int B = in_sizes[2] / (M_DIM * M_DIM);   // 64
    float* out = (float*)d_out;
    const unsigned int out_elems = (unsigned int)out_size;  // f32 elements

    const size_t partial_bytes = (size_t)B * CHUNKS * M_DIM * sizeof(float); // 2 MB
    const size_t u_bytes = (size_t)B * M_DIM * sizeof(float);                // 128 KB

    dim3 grid(B, CHUNKS);
    if (ws_size >= partial_bytes) {
        // Fast path: 2 kernels, partials in ws. (R8 lesson: a dependent-kernel
        // boundary is cheaper than any device-scope in-kernel barrier here.)
        float* partial = (float*)d_ws;
        kA_partial<<<grid, 256, 0, stream>>>(Lre, Tre, rho, partial);
        kB_expand<<<grid, 256, 0, stream>>>(partial, rho, tau, out, out_elems);
    } else if (ws_size >= u_bytes &&
               (size_t)out_size * sizeof(float) >= partial_bytes) {
        float* partial = out;
        float* u = (float*)d_ws;
        kA_partial<<<grid, 256, 0, stream>>>(Lre, Tre, rho, partial);
        k2_reduce<<<B, 256, 0, stream>>>(partial, rho, tau, u);
        k3_write<<<grid, 256, 0, stream>>>(u, out, out_elems);
    } else {
        k_fused<<<B, 256, 0, stream>>>(rho, tau, Lre, Tre, out, out_elems);
    }
}

// Round 12
// 29.552 us; speedup vs baseline: 4.4368x; 1.0993x over previous
//
#include <hip/hip_runtime.h>

typedef unsigned int uint32;
typedef float f32x4 __attribute__((ext_vector_type(4)));  // clang-native for nontemporal

#define M_DIM 512
#define CHUNKS 4    // partial arrays per batch (block.y of kA/kB)
#define LDSPAD 516  // kA LDS row: 512 data + 4 zero-pad (read offset cm<=3)

// ---------------------------------------------------------------------------
// Scalar decode (kept from ABI debugging; free): f32 1.0f has low16 == 0,
// a bf16 scalar would sit in the low 16 bits (nonzero).
// ---------------------------------------------------------------------------
__device__ __forceinline__ float dec_scalar(uint32 w) {
    return ((w & 0xFFFFu) == 0u) ? __uint_as_float(w)
                                 : __uint_as_float((w & 0xFFFFu) << 16);
}

// ---------------------------------------------------------------------------
// kA: partial real toeplitz-adjoint sums over diagonals d = j - i.
//   padj[b,c,d] = sum_{i == c (mod 4), i+d < M} (Lre[b,i,i+d] + rho*Tre[..])
// 1024 threads = 16 waves; wave w handles rows i = c + 4*(w + 16t), t<8.
// float4 loads from the 4-aligned row start a0 = i - c; lane register quad
// acc{0,1}[e] maps to STORED index si = 4*lane (+256) + e, diagonal
// d = si - c (constant shift per block!):
//   - si < c        -> lower-triangle garbage, excluded by the shifted read;
//   - d > 511 - c   -> si > 511 -> served by the 4-float zero pad.
// LDS scatter is one aligned ds_write_b128 per quad; reduce reads
// lds[w][d + c] (row-contiguous, conflict-free).
// ---------------------------------------------------------------------------
__global__ __launch_bounds__(1024) void kA_partial(
    const float* __restrict__ Lre, const float* __restrict__ Tre,
    const uint32* __restrict__ rho_p, float* __restrict__ partial)
{
    __shared__ float lds[16][LDSPAD];   // 33 KB
    const int b = blockIdx.x, c = blockIdx.y;          // c in [0,4)
    const int tid = threadIdx.x, w = tid >> 6, lane = tid & 63;
    const float rho = dec_scalar(rho_p[0]);

    const size_t base = (size_t)b * (M_DIM * M_DIM);

    f32x4 acc0 = {0.f, 0.f, 0.f, 0.f};
    f32x4 acc1 = {0.f, 0.f, 0.f, 0.f};

    for (int t = 0; t < 8; ++t) {                      // 8 rows per wave
        const int rw = w + 16 * t;                     // row index / 4
        const int i = c + 4 * rw;
        const int a0 = 4 * rw;                         // i - c, 4-aligned
        const int nq = 128 - rw;                       // valid float4s in row
        const float4* rowL = (const float4*)(Lre + base + (size_t)i * M_DIM + a0);
        const float4* rowT = (const float4*)(Tre + base + (size_t)i * M_DIM + a0);
        if (lane < nq) {
            const float4 L = rowL[lane];
            const float4 T = rowT[lane];
            acc0.x += L.x + rho * T.x;  acc0.y += L.y + rho * T.y;
            acc0.z += L.z + rho * T.z;  acc0.w += L.w + rho * T.w;
        }
        const int q1 = lane + 64;
        if (q1 < nq) {
            const float4 L = rowL[q1];
            const float4 T = rowT[q1];
            acc1.x += L.x + rho * T.x;  acc1.y += L.y + rho * T.y;
            acc1.z += L.z + rho * T.z;  acc1.w += L.w + rho * T.w;
        }
    }

    // aligned 16B LDS scatter: stored index si = 4*lane (+256)
    *(f32x4*)&lds[w][4 * lane]       = acc0;
    *(f32x4*)&lds[w][4 * lane + 256] = acc1;
    if (lane < 4) lds[w][512 + lane] = 0.0f;           // pad for d + c <= 515
    __syncthreads();

    // cross-wave reduce with the constant shift c: partial[d] = sum_w lds[w][d+c]
    if (tid < M_DIM) {
        const int d = tid;
        float s = 0.f;
        #pragma unroll
        for (int ww = 0; ww < 16; ++ww) s += lds[ww][d + c];
        partial[(size_t)(b * CHUNKS + c) * M_DIM + d] = s;
    }
}

// ---------------------------------------------------------------------------
// kB: per-block reduce of batch b's 4 partials (L2-hot, 8 KB) -> u_re in LDS
// -> write 128 rows: out[b,i,j] = u_re[|j-i|]. 1024 threads = 16 waves.
// LDS reads 8-way bank-conflicted but masked by store latency (R9-proven).
// Non-temporal stores: output is write-once, never re-read.
// ---------------------------------------------------------------------------
__global__ __launch_bounds__(1024) void kB_expand(
    const float* __restrict__ partial,
    const uint32* __restrict__ rho_p, const uint32* __restrict__ tau_p,
    float* __restrict__ out, unsigned int out_elems)
{
    __shared__ float ure[M_DIM];
    const int b = blockIdx.x, c = blockIdx.y;          // c in [0,4)
    const int tid = threadIdx.x;
    const float rho = dec_scalar(rho_p[0]);
    const float tau = dec_scalar(tau_p[0]);

    if (tid < M_DIM) {
        const int d = tid;
        const float* p = partial + (size_t)b * CHUNKS * M_DIM;
        float s = 0.f;
        #pragma unroll
        for (int cc = 0; cc < CHUNKS; ++cc) s += p[(size_t)cc * M_DIM + d];
        if (d == 0) s -= 0.5f * tau * (float)M_DIM;
        ure[d] = s / ((float)(M_DIM - d) * rho);
    }
    __syncthreads();

    const int w = tid >> 6, lane = tid & 63;
    for (int t = 0; t < 8; ++t) {                      // 8 rows per wave
        const int i = c * 128 + w * 8 + t;
        const size_t rbase = (size_t)(b * M_DIM + i) * M_DIM;
        if (rbase + M_DIM > (size_t)out_elems) continue; // safety clamp
        f32x4* rowp = (f32x4*)(out + rbase);
        #pragma unroll
        for (int k = 0; k < 2; ++k) {
            const int q = lane + (k << 6);
            const int j0 = q << 2;
            f32x4 v;
            #pragma unroll
            for (int e = 0; e < 4; ++e) {
                const int dd = j0 + e - i;
                v[e] = ure[dd < 0 ? -dd : dd];
            }
            __builtin_nontemporal_store(v, rowp + q);
        }
    }
}

// ---------------------------------------------------------------------------
// Mid fallback (ws in [128 KB, 512 KB)): partials transient in d_out.
// ---------------------------------------------------------------------------
__global__ __launch_bounds__(256) void k2_reduce(
    const float* __restrict__ partial,
    const uint32* __restrict__ rho_p, const uint32* __restrict__ tau_p,
    float* __restrict__ u)
{
    const int b = blockIdx.x, tid = threadIdx.x;
    const float rho = dec_scalar(rho_p[0]);
    const float tau = dec_scalar(tau_p[0]);
    const float* p = partial + (size_t)b * CHUNKS * M_DIM;
    for (int d = tid; d < M_DIM; d += 256) {
        float s = 0.f;
        #pragma unroll
        for (int cc = 0; cc < CHUNKS; ++cc) s += p[(size_t)cc * M_DIM + d];
        if (d == 0) s -= 0.5f * tau * (float)M_DIM;
        u[(size_t)b * M_DIM + d] = s / ((float)(M_DIM - d) * rho);
    }
}

__global__ __launch_bounds__(256) void k3_write(
    const float* __restrict__ u, float* __restrict__ out,
    unsigned int out_elems)
{
    __shared__ float ure[M_DIM];
    const int b = blockIdx.x, c = blockIdx.y, tid = threadIdx.x;  // c in [0,16)
    for (int d = tid; d < M_DIM; d += 256) ure[d] = u[(size_t)b * M_DIM + d];
    __syncthreads();
    const int w = tid >> 6, lane = tid & 63;
    for (int t = 0; t < 8; ++t) {
        const int i = c * 32 + w * 8 + t;
        const size_t rbase = (size_t)(b * M_DIM + i) * M_DIM;
        if (rbase + M_DIM > (size_t)out_elems) continue;
        float4* rowp = (float4*)(out + rbase);
        #pragma unroll
        for (int k = 0; k < 2; ++k) {
            const int q = lane + (k << 6);
            const int j0 = q << 2;
            float4 v;
            #pragma unroll
            for (int e = 0; e < 4; ++e) {
                const int dd = j0 + e - i;
                (&v.x)[e] = ure[dd < 0 ? -dd : dd];
            }
            rowp[q] = v;
        }
    }
}

// ---------------------------------------------------------------------------
// Zero-workspace fallback: one block per batch, fully fused.
// ---------------------------------------------------------------------------
__global__ __launch_bounds__(256) void k_fused(
    const uint32* __restrict__ rho_p, const uint32* __restrict__ tau_p,
    const float* __restrict__ Lre, const float* __restrict__ Tre,
    float* __restrict__ out, unsigned int out_elems)
{
    __shared__ float lds[4][M_DIM];
    __shared__ float ure[M_DIM];
    const int b = blockIdx.x, tid = threadIdx.x, w = tid >> 6, lane = tid & 63;
    const float rho = dec_scalar(rho_p[0]);
    const float tau = dec_scalar(tau_p[0]);

    float acc[8];
    #pragma unroll
    for (int k = 0; k < 8; ++k) acc[k] = 0.0f;
    const size_t base = (size_t)b * (M_DIM * M_DIM);
    for (int t = 0; t < M_DIM / 4; ++t) {
        const int i = w + 4 * t;
        const size_t roff = base + (size_t)i * M_DIM;
        const int dmax = (M_DIM - 1) - i;
        #pragma unroll
        for (int k = 0; k < 8; ++k) {
            const int d = lane + (k << 6);
            if (d <= dmax) {
                const size_t idx = roff + (size_t)(i + d);
                acc[k] += Lre[idx] + rho * Tre[idx];
            }
        }
    }
    #pragma unroll
    for (int k = 0; k < 8; ++k) lds[w][lane + (k << 6)] = acc[k];
    __syncthreads();

    for (int d = tid; d < M_DIM; d += 256) {
        float s = 0.f;
        #pragma unroll
        for (int ww = 0; ww < 4; ++ww) s += lds[ww][d];
        if (d == 0) s -= 0.5f * tau * (float)M_DIM;
        ure[d] = s / ((float)(M_DIM - d) * rho);
    }
    __syncthreads();

    for (int t = 0; t < M_DIM / 4; ++t) {
        const int i = w + 4 * t;
        const size_t rbase = (size_t)(b * M_DIM + i) * M_DIM;
        if (rbase + M_DIM > (size_t)out_elems) continue;
        float4* rowp = (float4*)(out + rbase);
        #pragma unroll
        for (int k = 0; k < 2; ++k) {
            const int q = lane + (k << 6);
            const int j0 = q << 2;
            float4 v;
            #pragma unroll
            for (int e = 0; e < 4; ++e) {
                const int dd = j0 + e - i;
                (&v.x)[e] = ure[dd < 0 ? -dd : dd];
            }
            rowp[q] = v;
        }
    }
}

extern "C" void kernel_launch(void* const* d_in, const int* in_sizes, int n_in,
                              void* d_out, int out_size, void* d_ws, size_t ws_size,
                              hipStream_t stream)
{
    const uint32* rho = (const uint32*)d_in[0];
    const uint32* tau = (const uint32*)d_in[1];
    const float* Lre = (const float*)d_in[2];
    // d_in[3] (Lamda_im), d_in[5] (Theta_im): never needed — output is re(T).
    const float* Tre = (const float*)d_in[4];
    const int B = in_sizes[2] / (M_DIM * M_DIM);   // 64
    float* out = (float*)d_out;
    const unsigned int out_elems = (unsigned int)out_size;  // f32 elements

    const size_t partial_bytes = (size_t)B * CHUNKS * M_DIM * sizeof(float); // 512 KB
    const size_t u_bytes = (size_t)B * M_DIM * sizeof(float);                // 128 KB

    dim3 grid(B, CHUNKS);
    if (ws_size >= partial_bytes) {
        // Fast path: 2 kernels, partials in ws. (R8 lesson: a dependent-kernel
        // boundary is cheaper than any device-scope in-kernel barrier here.)
        float* partial = (float*)d_ws;
        kA_partial<<<grid, 1024, 0, stream>>>(Lre, Tre, rho, partial);
        kB_expand<<<grid, 1024, 0, stream>>>(partial, rho, tau, out, out_elems);
    } else if (ws_size >= u_bytes &&
               (size_t)out_size * sizeof(float) >= partial_bytes) {
        float* partial = out;
        float* u = (float*)d_ws;
        kA_partial<<<grid, 1024, 0, stream>>>(Lre, Tre, rho, partial);
        k2_reduce<<<B, 256, 0, stream>>>(partial, rho, tau, u);
        k3_write<<<dim3(B, 16), 256, 0, stream>>>(u, out, out_elems);
    } else {
        k_fused<<<B, 256, 0, stream>>>(rho, tau, Lre, Tre, out, out_elems);
    }
}